// Round 10
// baseline (200.579 us; speedup 1.0000x reference)
//
#include <hip/hip_runtime.h>
#include <hip/hip_bf16.h>

// ---------------------------------------------------------------------------
// 2-layer single-head GAT encoder, N=50000, E=800000 (+N self loops)
// R8: 195 us. R9: 4x-MLP aggs + 4096-edge scatter -> 189 us.
// R10: (a) gemm1 alpha-dot: atomicAdd -> direct store (complete per block
//      since R8 two-pass) => as1/ad1 zeroing removed from prep_all;
//      (b) aggs 8 gathers in flight (agg128 j+=32, agg64 one j+=64 sweep).
// Fixed floor: ~44 us harness ws-poison fill per replay; aggs at compulsory
// cross-XCD L2-miss floor (~85 MB refetch, latency/outstanding-miss bound).
// segment_max skipped: logits bounded, unshifted exp exact after normalize.
// ---------------------------------------------------------------------------

#define BCAP 4096

typedef __attribute__((ext_vector_type(8))) short bf16x8;
typedef __attribute__((ext_vector_type(4))) float f32x4;

__device__ __forceinline__ unsigned short bf16bits(float f){
  __hip_bfloat16 b = __float2bfloat16(f);
  return *(unsigned short*)&b;
}
__device__ __forceinline__ float bf16lo(unsigned int v){ return __uint_as_float(v << 16); }
__device__ __forceinline__ float bf16hi(unsigned int v){ return __uint_as_float(v & 0xFFFF0000u); }

// --- prep: W transposes (bf16), va_s/va_d = W2^T a2x, zero bucketCount ---
__global__ __launch_bounds__(256) void prep_all(
    const float* __restrict__ W1, const float* __restrict__ W2,
    const float* __restrict__ a2s, const float* __restrict__ a2d,
    unsigned short* __restrict__ W1t, unsigned short* __restrict__ W2t,
    float* __restrict__ vas, float* __restrict__ vad,
    int* __restrict__ bucketCount)
{
  int b = blockIdx.x, t = threadIdx.x;
  if (b < 48){
    int idx = b*256 + t;               // ushort2 index
    if (idx < 8192){                   // W1t: [n][k], n<128, K=128
      int n = idx >> 6, k2 = idx & 63;
      float a = W1[(size_t)(2*k2)*128 + n];
      float c = W1[(size_t)(2*k2+1)*128 + n];
      ushort2 o; o.x = bf16bits(a); o.y = bf16bits(c);
      *(ushort2*)&W1t[(size_t)n*128 + 2*k2] = o;
    } else {                           // W2t: [n][k], n<64, K=128
      int r = idx - 8192;              // < 4096
      int n = r >> 6, k2 = r & 63;
      float a = W2[(size_t)(2*k2)*64 + n];
      float c = W2[(size_t)(2*k2+1)*64 + n];
      ushort2 o; o.x = bf16bits(a); o.y = bf16bits(c);
      *(ushort2*)&W2t[(size_t)n*128 + 2*k2] = o;
    }
  } else if (b == 48){                 // va_s / va_d (128 each)
    int k = t & 127;
    const float* av = (t < 128) ? a2s : a2d;
    float* ov = (t < 128) ? vas : vad;
    float s = 0.f;
    for (int n=0; n<64; n++) s += W2[(size_t)k*64 + n] * av[n];
    ov[k] = s;
  } else {                             // block 49: bucketCount zero (512 ints)
    bucketCount[t] = 0; bucketCount[t+256] = 0;
  }
}

// --- gemm body: H = A @ W (MFMA bf16, fp32 acc), two-pass over 64-col halves;
//     optional fused alpha-dot epilogue (direct store — complete per block).
template<int NC, bool FUSE>
__device__ __forceinline__ void gemm_body(
    const float* __restrict__ Af, const unsigned short* __restrict__ Ah,
    const unsigned short* __restrict__ Wt,
    const float* __restrict__ avs, const float* __restrict__ avd,
    unsigned short* __restrict__ H, float* __restrict__ as_, float* __restrict__ ad_,
    int M, int rowBase, unsigned short* As, unsigned short* Ws)
{
  const int K = 128;
  int t = threadIdx.x;
  if (Af){                     // fp32 A -> convert
    #pragma unroll
    for (int i=0;i<8;i++){
      int idx = t + i*256; int r = idx>>5, k4 = idx&31;
      int grow = rowBase + r;
      float4 v = (grow<M) ? *(const float4*)&Af[(size_t)grow*K + k4*4]
                          : make_float4(0.f,0.f,0.f,0.f);
      ushort4 o; o.x=bf16bits(v.x); o.y=bf16bits(v.y); o.z=bf16bits(v.z); o.w=bf16bits(v.w);
      *(ushort4*)&As[r*136 + k4*4] = o;
    }
  } else {
    #pragma unroll
    for (int i=0;i<4;i++){
      int idx = t + i*256; int r = idx>>4, k8 = idx&15;
      int grow = rowBase + r;
      uint4 v = (grow<M) ? *(const uint4*)&Ah[(size_t)grow*K + k8*8]
                         : make_uint4(0u,0u,0u,0u);
      *(uint4*)&As[r*136 + k8*8] = v;
    }
  }
  int wave = t>>6, lane = t&63, ln = lane&15, q = lane>>4;
  f32x4 acc[NC/16];
  #pragma unroll
  for (int nt=0; nt<NC/16; nt++) acc[nt] = (f32x4){0.f,0.f,0.f,0.f};

  #pragma unroll
  for (int ch=0; ch<NC/64; ++ch){
    __syncthreads();               // Ws reuse guard
    #pragma unroll
    for (int i=0;i<4;i++){
      int idx = t + i*256; int n = idx>>4, k8 = idx&15;
      *(uint4*)&Ws[n*136 + k8*8] = *(const uint4*)&Wt[(size_t)(ch*64+n)*K + k8*8];
    }
    __syncthreads();               // covers As staging (ch=0) + Ws staging
    #pragma unroll
    for (int kk=0;kk<4;kk++){
      bf16x8 a = *(const bf16x8*)&As[(wave*16+ln)*136 + kk*32 + q*8];
      #pragma unroll
      for (int nt=0; nt<4; nt++){
        bf16x8 b = *(const bf16x8*)&Ws[(nt*16+ln)*136 + kk*32 + q*8];
        acc[ch*4+nt] = __builtin_amdgcn_mfma_f32_16x16x32_bf16(a, b, acc[ch*4+nt], 0, 0, 0);
      }
    }
  }
  // epilogue: C/D layout col=lane&15, row=(lane>>4)*4+i
  float asl[NC/16], adl[NC/16];
  if (FUSE){
    #pragma unroll
    for (int nt=0; nt<NC/16; nt++){ asl[nt]=avs[nt*16+ln]; adl[nt]=avd[nt*16+ln]; }
  }
  #pragma unroll
  for (int i=0;i<4;i++){
    int grow = rowBase + wave*16 + q*4 + i;
    if (grow < M){
      float ps=0.f, pd=0.f;
      #pragma unroll
      for (int nt=0; nt<NC/16; nt++){
        float v = acc[nt][i];
        H[(size_t)grow*NC + nt*16 + ln] = bf16bits(v);
        if (FUSE){ ps += v*asl[nt]; pd += v*adl[nt]; }
      }
      if (FUSE){
        #pragma unroll
        for (int d=1; d<16; d<<=1){ ps += __shfl_xor(ps,d); pd += __shfl_xor(pd,d); }
        if (ln==0){ as_[grow] = ps; ad_[grow] = pd; }   // full row dot: direct store
      }
    }
  }
}

// --- heterogeneous: blocks [0,SB) coarse-bucket edges (4096/block);
//     blocks [SB,..) gemm1 ---
__global__ __launch_bounds__(256) void scatter_or_gemm(
    const int* __restrict__ src, const int* __restrict__ dst,
    int* __restrict__ bucketCount, unsigned int* __restrict__ gbuf, int E, int SB,
    const float* __restrict__ x, const unsigned short* __restrict__ W1t,
    const float* __restrict__ a1s, const float* __restrict__ a1d,
    unsigned short* __restrict__ h1, float* __restrict__ as1, float* __restrict__ ad1,
    int M)
{
  __shared__ unsigned short smem[64*136 + 64*136];    // 34816 B
  int t = threadIdx.x;
  if ((int)blockIdx.x >= SB){
    gemm_body<128, true>(x, nullptr, W1t, a1s, a1d, h1, as1, ad1, M,
                         (blockIdx.x - SB)*64, smem, smem + 64*136);
    return;
  }
  int* hist = (int*)smem;          // 512 ints
  int* base = hist + 512;          // 512 ints
  int e0 = blockIdx.x * 4096;
  hist[t] = 0; hist[t+256] = 0;
  __syncthreads();
  int sv[16], dv[16];
  #pragma unroll
  for (int k=0;k<16;k++){
    int i = e0 + t + k*256;
    if (i < E){ sv[k]=src[i]; dv[k]=dst[i]; atomicAdd(&hist[dv[k]>>7], 1); }
    else { sv[k] = -1; dv[k] = 0; }
  }
  __syncthreads();
  int h0 = hist[t], h1c = hist[t+256];
  if (h0 > 0)  base[t]     = atomicAdd(&bucketCount[t],     h0);
  if (h1c > 0) base[t+256] = atomicAdd(&bucketCount[t+256], h1c);
  __syncthreads();
  hist[t] = 0; hist[t+256] = 0;
  __syncthreads();
  #pragma unroll
  for (int k=0;k<16;k++){
    if (sv[k] >= 0){
      int b = dv[k] >> 7;
      int r = base[b] + atomicAdd(&hist[b], 1);
      if (r < BCAP)
        gbuf[(size_t)b*BCAP + r] = ((unsigned)(dv[k] & 127) << 16) | (unsigned)sv[k];
    }
  }
}

// --- fine sort (512 thr): self-scan of bucket sizes, counting sort into CSR ---
__global__ __launch_bounds__(512) void fine_sort(
    const unsigned int* __restrict__ gbuf, const int* __restrict__ bucketCount,
    int* __restrict__ offs, int* __restrict__ srcS, int N, int E, int B)
{
  __shared__ int sh[512];
  __shared__ int h[128];
  __shared__ int pre[128];
  __shared__ int rank[128];
  int b = blockIdx.x, t = threadIdx.x;
  {
    int nd_t = 0;
    if (t < B){ int lo=t*128; nd_t = (N-lo<128)?(N-lo):128; }
    sh[t] = (t < B ? bucketCount[t] : 0) + nd_t;
    __syncthreads();
    for (int d=1; d<512; d<<=1){
      int x = (t >= d) ? sh[t-d] : 0;
      __syncthreads();
      sh[t] += x;
      __syncthreads();
    }
  }
  int cnt = bucketCount[b]; if (cnt > BCAP) cnt = BCAP;
  int lo = b*128;
  int nd = (N - lo < 128) ? (N - lo) : 128;
  int base = sh[b] - (cnt + nd);       // exclusive prefix
  if (b == 0 && t == 0) offs[N] = E + N;
  if (t < 128){ h[t] = 0; rank[t] = 0; }
  __syncthreads();
  for (int i = t; i < cnt; i += 512)
    atomicAdd(&h[(gbuf[(size_t)b*BCAP + i] >> 16) & 127], 1);
  __syncthreads();
  if (t < 128) pre[t] = (t < nd) ? (h[t] + 1) : 0;
  __syncthreads();
  for (int d=1; d<128; d<<=1){
    int x = (t >= d && t < 128) ? pre[t-d] : 0;
    __syncthreads();
    if (t < 128) pre[t] += x;
    __syncthreads();
  }
  int seg = (t < nd) ? (h[t] + 1) : 0;
  int ex  = (t < 128) ? (pre[t] - seg) : 0;
  if (t < nd){
    offs[lo + t] = base + ex;
    srcS[base + ex] = lo + t;          // self loop first
  }
  __syncthreads();
  if (t < 128) pre[t] = ex;
  __syncthreads();
  for (int i = t; i < cnt; i += 512){
    unsigned e = gbuf[(size_t)b*BCAP + i];
    int dl = (e >> 16) & 127;
    int s  = e & 0xFFFF;
    int r  = atomicAdd(&rank[dl], 1);
    srcS[base + pre[dl] + 1 + r] = s;
  }
}

// --- F=128 aggregation + fused layer-2 logits: quarter-waves, 32 edges/iter
//     (8 uint4 gathers in flight) ---
__global__ __launch_bounds__(256) void edge_agg128(
    const int* __restrict__ offs, const int* __restrict__ srcS,
    const float* __restrict__ asrc, const float* __restrict__ adst,
    const unsigned short* __restrict__ Hin, const float* __restrict__ bias,
    unsigned short* __restrict__ outp,
    const float* __restrict__ vas, const float* __restrict__ vad,
    float* __restrict__ as2, float* __restrict__ ad2, int n)
{
  int wid  = (blockIdx.x * 256 + threadIdx.x) >> 6;
  int lane = threadIdx.x & 63;
  if (wid >= n) return;
  int beg = offs[wid], end = offs[wid+1];
  float ad = adst[wid];
  int qw = lane >> 4, ql = lane & 15;
  float acc[8] = {}; float denom = 0.f;
  for (int base = beg; base < end; base += 64){
    int m = end - base; if (m > 64) m = 64;
    int   sv = (lane < m) ? srcS[base + lane] : 0;
    float av = (lane < m) ? asrc[sv] : 0.f;
    float ev = av + ad;
    ev = (ev > 0.f) ? ev : 0.2f*ev;
    float wv = (lane < m) ? __expf(ev) : 0.f;
    for (int j = 0; j < m; j += 32){
      int   s[8]; float wt[8]; uint4 hv[8];
      #pragma unroll
      for (int g=0; g<8; g++){
        int idx = j + g*4 + qw;                      // <=63
        s[g] = __shfl(sv, idx);
        wt[g] = __shfl(wv, idx);                     // 0 beyond m
      }
      #pragma unroll
      for (int g=0; g<8; g++)
        hv[g] = *(const uint4*)&Hin[(size_t)s[g]*128 + ql*8];
      #pragma unroll
      for (int g=0; g<8; g++){
        float w = wt[g];
        denom += w;
        acc[0]+=w*bf16lo(hv[g].x); acc[1]+=w*bf16hi(hv[g].x);
        acc[2]+=w*bf16lo(hv[g].y); acc[3]+=w*bf16hi(hv[g].y);
        acc[4]+=w*bf16lo(hv[g].z); acc[5]+=w*bf16hi(hv[g].z);
        acc[6]+=w*bf16lo(hv[g].w); acc[7]+=w*bf16hi(hv[g].w);
      }
    }
  }
  denom += __shfl_xor(denom,16); denom += __shfl_xor(denom,32);
  #pragma unroll
  for (int k=0;k<8;k++){ acc[k]+=__shfl_xor(acc[k],16); acc[k]+=__shfl_xor(acc[k],32); }
  if (qw == 0){
    float inv = 1.0f / denom;          // >=1 term (self loop)
    float ps = 0.f, pd = 0.f;
    unsigned short o[8];
    #pragma unroll
    for (int k=0;k<8;k++){
      float v = fmaxf(acc[k]*inv + bias[ql*8+k], 0.f);   // relu (layer1 only)
      o[k] = bf16bits(v);
      ps += v * vas[ql*8+k];
      pd += v * vad[ql*8+k];
    }
    *(uint4*)&outp[(size_t)wid*128 + ql*8] = *(uint4*)o;
    #pragma unroll
    for (int d=1; d<16; d<<=1){ ps += __shfl_xor(ps,d); pd += __shfl_xor(pd,d); }
    if (ql == 0){ as2[wid] = ps; ad2[wid] = pd; }
  }
}

// --- gemm2: h2 = hrelu @ W2 (no alpha fusion) ---
__global__ __launch_bounds__(256) void gemm2_k(
    const unsigned short* __restrict__ A, const unsigned short* __restrict__ Wt,
    unsigned short* __restrict__ H, int M)
{
  __shared__ unsigned short smem[64*136 + 64*136];
  gemm_body<64, false>(nullptr, A, Wt, nullptr, nullptr, H, nullptr, nullptr,
                       M, blockIdx.x*64, smem, smem + 64*136);
}

// --- F=64 aggregation: eighth-waves, full 64-edge sweep (8 gathers in flight) ---
__global__ __launch_bounds__(256) void edge_agg64(
    const int* __restrict__ offs, const int* __restrict__ srcS,
    const float* __restrict__ asrc, const float* __restrict__ adst,
    const unsigned short* __restrict__ Hin, const float* __restrict__ bias,
    float* __restrict__ outp, int n)
{
  int wid  = (blockIdx.x * 256 + threadIdx.x) >> 6;
  int lane = threadIdx.x & 63;
  if (wid >= n) return;
  int beg = offs[wid], end = offs[wid+1];
  float ad = adst[wid];
  int ew = lane >> 3, el = lane & 7;
  float acc[8] = {}; float denom = 0.f;
  for (int base = beg; base < end; base += 64){
    int m = end - base; if (m > 64) m = 64;
    int   sv = (lane < m) ? srcS[base + lane] : 0;
    float av = (lane < m) ? asrc[sv] : 0.f;
    float ev = av + ad;
    ev = (ev > 0.f) ? ev : 0.2f*ev;
    float wv = (lane < m) ? __expf(ev) : 0.f;
    int   s[8]; float wt[8]; uint4 hv[8];
    #pragma unroll
    for (int g=0; g<8; g++){
      int idx = g*8 + ew;                            // <=63, covers all 64
      s[g] = __shfl(sv, idx);
      wt[g] = __shfl(wv, idx);
    }
    #pragma unroll
    for (int g=0; g<8; g++)
      hv[g] = *(const uint4*)&Hin[(size_t)s[g]*64 + el*8];
    #pragma unroll
    for (int g=0; g<8; g++){
      float w = wt[g];
      denom += w;
      acc[0]+=w*bf16lo(hv[g].x); acc[1]+=w*bf16hi(hv[g].x);
      acc[2]+=w*bf16lo(hv[g].y); acc[3]+=w*bf16hi(hv[g].y);
      acc[4]+=w*bf16lo(hv[g].z); acc[5]+=w*bf16hi(hv[g].z);
      acc[6]+=w*bf16lo(hv[g].w); acc[7]+=w*bf16hi(hv[g].w);
    }
  }
  denom += __shfl_xor(denom,8); denom += __shfl_xor(denom,16); denom += __shfl_xor(denom,32);
  #pragma unroll
  for (int k=0;k<8;k++){
    acc[k]+=__shfl_xor(acc[k],8); acc[k]+=__shfl_xor(acc[k],16); acc[k]+=__shfl_xor(acc[k],32);
  }
  if (ew == 0){
    float inv = 1.0f / denom;
    float4 o0, o1;
    o0.x = acc[0]*inv + bias[el*8+0]; o0.y = acc[1]*inv + bias[el*8+1];
    o0.z = acc[2]*inv + bias[el*8+2]; o0.w = acc[3]*inv + bias[el*8+3];
    o1.x = acc[4]*inv + bias[el*8+4]; o1.y = acc[5]*inv + bias[el*8+5];
    o1.z = acc[6]*inv + bias[el*8+6]; o1.w = acc[7]*inv + bias[el*8+7];
    *(float4*)&outp[(size_t)wid*64 + el*8]     = o0;
    *(float4*)&outp[(size_t)wid*64 + el*8 + 4] = o1;
  }
}

extern "C" void kernel_launch(void* const* d_in, const int* in_sizes, int n_in,
                              void* d_out, int out_size, void* d_ws, size_t ws_size,
                              hipStream_t stream) {
  const int IN = 128, HID = 128, OUT = 64;
  const int N = in_sizes[0] / IN;        // 50000
  const int E = in_sizes[1] / 2;         // 800000
  const int B = (N + 127) / 128;         // 391 buckets (<=512)
  const int SB = (E + 4095) / 4096;      // 196 scatter blocks

  const float* x    = (const float*)d_in[0];
  const int*   ei   = (const int*)d_in[1];
  const float* W1   = (const float*)d_in[2];
  const float* a1s  = (const float*)d_in[3];
  const float* a1d  = (const float*)d_in[4];
  const float* b1   = (const float*)d_in[5];
  const float* W2   = (const float*)d_in[6];
  const float* a2s  = (const float*)d_in[7];
  const float* a2d  = (const float*)d_in[8];
  const float* b2   = (const float*)d_in[9];
  float* out = (float*)d_out;

  char* w = (char*)d_ws;
  unsigned short* W1t = (unsigned short*)w; w += (size_t)HID*IN*2;
  unsigned short* W2t = (unsigned short*)w; w += (size_t)OUT*HID*2;
  unsigned short* h1    = (unsigned short*)w; w += (size_t)N*128*2;  // bf16
  unsigned short* hrelu = (unsigned short*)w; w += (size_t)N*128*2;  // bf16
  unsigned short* h2 = h1;               // alias: h1 dead before gemm2 writes h2
  float* as1   = (float*)w; w += (size_t)N*4;   // direct-stored by gemm1
  float* ad1   = (float*)w; w += (size_t)N*4;
  float* as2   = (float*)w; w += (size_t)N*4;   // direct-stored by edge_agg128
  float* ad2   = (float*)w; w += (size_t)N*4;
  float* vas   = (float*)w; w += 128*4;
  float* vad   = (float*)w; w += 128*4;
  int* offs    = (int*)w;   w += (size_t)(N+1)*4;
  int* bucketCount = (int*)w; w += 512*4;
  int* srcS    = (int*)w;   w += (size_t)(E+N)*4;
  unsigned int* gbuf = (unsigned int*)w; w += (size_t)B*BCAP*4;

  const int* esrc = ei;
  const int* edst = ei + E;

  hipLaunchKernelGGL(prep_all, dim3(50), dim3(256), 0, stream,
                     W1, W2, a2s, a2d, W1t, W2t, vas, vad, bucketCount);
  hipLaunchKernelGGL(scatter_or_gemm, dim3(SB + (N+63)/64), dim3(256), 0, stream,
                     esrc, edst, bucketCount, gbuf, E, SB,
                     x, W1t, a1s, a1d, h1, as1, ad1, N);
  hipLaunchKernelGGL(fine_sort, dim3(B), dim3(512), 0, stream,
                     gbuf, bucketCount, offs, srcS, N, E, B);
  hipLaunchKernelGGL(edge_agg128, dim3((N*64+255)/256), dim3(256), 0, stream,
                     offs, srcS, as1, ad1, h1, b1, hrelu, vas, vad, as2, ad2, N);
  hipLaunchKernelGGL(gemm2_k, dim3((N+63)/64), dim3(256), 0, stream,
                     hrelu, W2t, h2, N);
  hipLaunchKernelGGL(edge_agg64, dim3((N*64+255)/256), dim3(256), 0, stream,
                     offs, srcS, as2, ad2, h2, b2, out, N);
}

// Round 11
// 184.603 us; speedup vs baseline: 1.0865x; 1.0865x over previous
//
#include <hip/hip_runtime.h>
#include <hip/hip_bf16.h>

// ---------------------------------------------------------------------------
// 2-layer single-head GAT encoder, N=50000, E=800000 (+N self loops)
// R9: 189 us (4 gathers in flight). R10: 8 gathers -> 200.6 us REGRESSION
//     (edge_agg128 44us, VALUBusy 57% — VALU-bound, compiler serialized).
// R11: aggs reverted to R9's 4-gather config; keep R10's direct-store alpha
//      dots (no atomics, no as1/ad1 zeroing).
// Fixed floor: ~44 us harness ws-poison fill; aggs at compulsory cross-XCD
// L2-miss refetch floor (~84 MB); sort at ~1.5x write-amp floor.
// segment_max skipped: logits bounded, unshifted exp exact after normalize.
// ---------------------------------------------------------------------------

#define BCAP 4096

typedef __attribute__((ext_vector_type(8))) short bf16x8;
typedef __attribute__((ext_vector_type(4))) float f32x4;

__device__ __forceinline__ unsigned short bf16bits(float f){
  __hip_bfloat16 b = __float2bfloat16(f);
  return *(unsigned short*)&b;
}
__device__ __forceinline__ float bf16lo(unsigned int v){ return __uint_as_float(v << 16); }
__device__ __forceinline__ float bf16hi(unsigned int v){ return __uint_as_float(v & 0xFFFF0000u); }

// --- prep: W transposes (bf16), va_s/va_d = W2^T a2x, zero bucketCount ---
__global__ __launch_bounds__(256) void prep_all(
    const float* __restrict__ W1, const float* __restrict__ W2,
    const float* __restrict__ a2s, const float* __restrict__ a2d,
    unsigned short* __restrict__ W1t, unsigned short* __restrict__ W2t,
    float* __restrict__ vas, float* __restrict__ vad,
    int* __restrict__ bucketCount)
{
  int b = blockIdx.x, t = threadIdx.x;
  if (b < 48){
    int idx = b*256 + t;               // ushort2 index
    if (idx < 8192){                   // W1t: [n][k], n<128, K=128
      int n = idx >> 6, k2 = idx & 63;
      float a = W1[(size_t)(2*k2)*128 + n];
      float c = W1[(size_t)(2*k2+1)*128 + n];
      ushort2 o; o.x = bf16bits(a); o.y = bf16bits(c);
      *(ushort2*)&W1t[(size_t)n*128 + 2*k2] = o;
    } else {                           // W2t: [n][k], n<64, K=128
      int r = idx - 8192;              // < 4096
      int n = r >> 6, k2 = r & 63;
      float a = W2[(size_t)(2*k2)*64 + n];
      float c = W2[(size_t)(2*k2+1)*64 + n];
      ushort2 o; o.x = bf16bits(a); o.y = bf16bits(c);
      *(ushort2*)&W2t[(size_t)n*128 + 2*k2] = o;
    }
  } else if (b == 48){                 // va_s / va_d (128 each)
    int k = t & 127;
    const float* av = (t < 128) ? a2s : a2d;
    float* ov = (t < 128) ? vas : vad;
    float s = 0.f;
    for (int n=0; n<64; n++) s += W2[(size_t)k*64 + n] * av[n];
    ov[k] = s;
  } else {                             // block 49: bucketCount zero (512 ints)
    bucketCount[t] = 0; bucketCount[t+256] = 0;
  }
}

// --- gemm body: H = A @ W (MFMA bf16, fp32 acc), two-pass over 64-col halves;
//     optional fused alpha-dot epilogue (direct store — complete per block).
template<int NC, bool FUSE>
__device__ __forceinline__ void gemm_body(
    const float* __restrict__ Af, const unsigned short* __restrict__ Ah,
    const unsigned short* __restrict__ Wt,
    const float* __restrict__ avs, const float* __restrict__ avd,
    unsigned short* __restrict__ H, float* __restrict__ as_, float* __restrict__ ad_,
    int M, int rowBase, unsigned short* As, unsigned short* Ws)
{
  const int K = 128;
  int t = threadIdx.x;
  if (Af){                     // fp32 A -> convert
    #pragma unroll
    for (int i=0;i<8;i++){
      int idx = t + i*256; int r = idx>>5, k4 = idx&31;
      int grow = rowBase + r;
      float4 v = (grow<M) ? *(const float4*)&Af[(size_t)grow*K + k4*4]
                          : make_float4(0.f,0.f,0.f,0.f);
      ushort4 o; o.x=bf16bits(v.x); o.y=bf16bits(v.y); o.z=bf16bits(v.z); o.w=bf16bits(v.w);
      *(ushort4*)&As[r*136 + k4*4] = o;
    }
  } else {
    #pragma unroll
    for (int i=0;i<4;i++){
      int idx = t + i*256; int r = idx>>4, k8 = idx&15;
      int grow = rowBase + r;
      uint4 v = (grow<M) ? *(const uint4*)&Ah[(size_t)grow*K + k8*8]
                         : make_uint4(0u,0u,0u,0u);
      *(uint4*)&As[r*136 + k8*8] = v;
    }
  }
  int wave = t>>6, lane = t&63, ln = lane&15, q = lane>>4;
  f32x4 acc[NC/16];
  #pragma unroll
  for (int nt=0; nt<NC/16; nt++) acc[nt] = (f32x4){0.f,0.f,0.f,0.f};

  #pragma unroll
  for (int ch=0; ch<NC/64; ++ch){
    __syncthreads();               // Ws reuse guard
    #pragma unroll
    for (int i=0;i<4;i++){
      int idx = t + i*256; int n = idx>>4, k8 = idx&15;
      *(uint4*)&Ws[n*136 + k8*8] = *(const uint4*)&Wt[(size_t)(ch*64+n)*K + k8*8];
    }
    __syncthreads();               // covers As staging (ch=0) + Ws staging
    #pragma unroll
    for (int kk=0;kk<4;kk++){
      bf16x8 a = *(const bf16x8*)&As[(wave*16+ln)*136 + kk*32 + q*8];
      #pragma unroll
      for (int nt=0; nt<4; nt++){
        bf16x8 b = *(const bf16x8*)&Ws[(nt*16+ln)*136 + kk*32 + q*8];
        acc[ch*4+nt] = __builtin_amdgcn_mfma_f32_16x16x32_bf16(a, b, acc[ch*4+nt], 0, 0, 0);
      }
    }
  }
  // epilogue: C/D layout col=lane&15, row=(lane>>4)*4+i
  float asl[NC/16], adl[NC/16];
  if (FUSE){
    #pragma unroll
    for (int nt=0; nt<NC/16; nt++){ asl[nt]=avs[nt*16+ln]; adl[nt]=avd[nt*16+ln]; }
  }
  #pragma unroll
  for (int i=0;i<4;i++){
    int grow = rowBase + wave*16 + q*4 + i;
    if (grow < M){
      float ps=0.f, pd=0.f;
      #pragma unroll
      for (int nt=0; nt<NC/16; nt++){
        float v = acc[nt][i];
        H[(size_t)grow*NC + nt*16 + ln] = bf16bits(v);
        if (FUSE){ ps += v*asl[nt]; pd += v*adl[nt]; }
      }
      if (FUSE){
        #pragma unroll
        for (int d=1; d<16; d<<=1){ ps += __shfl_xor(ps,d); pd += __shfl_xor(pd,d); }
        if (ln==0){ as_[grow] = ps; ad_[grow] = pd; }   // full row dot: direct store
      }
    }
  }
}

// --- heterogeneous: blocks [0,SB) coarse-bucket edges (4096/block);
//     blocks [SB,..) gemm1 ---
__global__ __launch_bounds__(256) void scatter_or_gemm(
    const int* __restrict__ src, const int* __restrict__ dst,
    int* __restrict__ bucketCount, unsigned int* __restrict__ gbuf, int E, int SB,
    const float* __restrict__ x, const unsigned short* __restrict__ W1t,
    const float* __restrict__ a1s, const float* __restrict__ a1d,
    unsigned short* __restrict__ h1, float* __restrict__ as1, float* __restrict__ ad1,
    int M)
{
  __shared__ unsigned short smem[64*136 + 64*136];    // 34816 B
  int t = threadIdx.x;
  if ((int)blockIdx.x >= SB){
    gemm_body<128, true>(x, nullptr, W1t, a1s, a1d, h1, as1, ad1, M,
                         (blockIdx.x - SB)*64, smem, smem + 64*136);
    return;
  }
  int* hist = (int*)smem;          // 512 ints
  int* base = hist + 512;          // 512 ints
  int e0 = blockIdx.x * 4096;
  hist[t] = 0; hist[t+256] = 0;
  __syncthreads();
  int sv[16], dv[16];
  #pragma unroll
  for (int k=0;k<16;k++){
    int i = e0 + t + k*256;
    if (i < E){ sv[k]=src[i]; dv[k]=dst[i]; atomicAdd(&hist[dv[k]>>7], 1); }
    else { sv[k] = -1; dv[k] = 0; }
  }
  __syncthreads();
  int h0 = hist[t], h1c = hist[t+256];
  if (h0 > 0)  base[t]     = atomicAdd(&bucketCount[t],     h0);
  if (h1c > 0) base[t+256] = atomicAdd(&bucketCount[t+256], h1c);
  __syncthreads();
  hist[t] = 0; hist[t+256] = 0;
  __syncthreads();
  #pragma unroll
  for (int k=0;k<16;k++){
    if (sv[k] >= 0){
      int b = dv[k] >> 7;
      int r = base[b] + atomicAdd(&hist[b], 1);
      if (r < BCAP)
        gbuf[(size_t)b*BCAP + r] = ((unsigned)(dv[k] & 127) << 16) | (unsigned)sv[k];
    }
  }
}

// --- fine sort (512 thr): self-scan of bucket sizes, counting sort into CSR ---
__global__ __launch_bounds__(512) void fine_sort(
    const unsigned int* __restrict__ gbuf, const int* __restrict__ bucketCount,
    int* __restrict__ offs, int* __restrict__ srcS, int N, int E, int B)
{
  __shared__ int sh[512];
  __shared__ int h[128];
  __shared__ int pre[128];
  __shared__ int rank[128];
  int b = blockIdx.x, t = threadIdx.x;
  {
    int nd_t = 0;
    if (t < B){ int lo=t*128; nd_t = (N-lo<128)?(N-lo):128; }
    sh[t] = (t < B ? bucketCount[t] : 0) + nd_t;
    __syncthreads();
    for (int d=1; d<512; d<<=1){
      int x = (t >= d) ? sh[t-d] : 0;
      __syncthreads();
      sh[t] += x;
      __syncthreads();
    }
  }
  int cnt = bucketCount[b]; if (cnt > BCAP) cnt = BCAP;
  int lo = b*128;
  int nd = (N - lo < 128) ? (N - lo) : 128;
  int base = sh[b] - (cnt + nd);       // exclusive prefix
  if (b == 0 && t == 0) offs[N] = E + N;
  if (t < 128){ h[t] = 0; rank[t] = 0; }
  __syncthreads();
  for (int i = t; i < cnt; i += 512)
    atomicAdd(&h[(gbuf[(size_t)b*BCAP + i] >> 16) & 127], 1);
  __syncthreads();
  if (t < 128) pre[t] = (t < nd) ? (h[t] + 1) : 0;
  __syncthreads();
  for (int d=1; d<128; d<<=1){
    int x = (t >= d && t < 128) ? pre[t-d] : 0;
    __syncthreads();
    if (t < 128) pre[t] += x;
    __syncthreads();
  }
  int seg = (t < nd) ? (h[t] + 1) : 0;
  int ex  = (t < 128) ? (pre[t] - seg) : 0;
  if (t < nd){
    offs[lo + t] = base + ex;
    srcS[base + ex] = lo + t;          // self loop first
  }
  __syncthreads();
  if (t < 128) pre[t] = ex;
  __syncthreads();
  for (int i = t; i < cnt; i += 512){
    unsigned e = gbuf[(size_t)b*BCAP + i];
    int dl = (e >> 16) & 127;
    int s  = e & 0xFFFF;
    int r  = atomicAdd(&rank[dl], 1);
    srcS[base + pre[dl] + 1 + r] = s;
  }
}

// --- F=128 aggregation + fused layer-2 logits: quarter-waves, 16 edges/iter
//     (4 uint4 gathers in flight — measured sweet spot) ---
__global__ __launch_bounds__(256) void edge_agg128(
    const int* __restrict__ offs, const int* __restrict__ srcS,
    const float* __restrict__ asrc, const float* __restrict__ adst,
    const unsigned short* __restrict__ Hin, const float* __restrict__ bias,
    unsigned short* __restrict__ outp,
    const float* __restrict__ vas, const float* __restrict__ vad,
    float* __restrict__ as2, float* __restrict__ ad2, int n)
{
  int wid  = (blockIdx.x * 256 + threadIdx.x) >> 6;
  int lane = threadIdx.x & 63;
  if (wid >= n) return;
  int beg = offs[wid], end = offs[wid+1];
  float ad = adst[wid];
  int qw = lane >> 4, ql = lane & 15;
  float acc[8] = {}; float denom = 0.f;
  for (int base = beg; base < end; base += 64){
    int m = end - base; if (m > 64) m = 64;
    int   sv = (lane < m) ? srcS[base + lane] : 0;
    float av = (lane < m) ? asrc[sv] : 0.f;
    float ev = av + ad;
    ev = (ev > 0.f) ? ev : 0.2f*ev;
    float wv = (lane < m) ? __expf(ev) : 0.f;
    for (int j = 0; j < m; j += 16){
      int i0 = j+qw, i1 = j+4+qw, i2 = j+8+qw, i3 = j+12+qw;    // <=63
      int   s0 = __shfl(sv,i0), s1 = __shfl(sv,i1), s2 = __shfl(sv,i2), s3 = __shfl(sv,i3);
      float w0 = __shfl(wv,i0), w1 = __shfl(wv,i1), w2 = __shfl(wv,i2), w3 = __shfl(wv,i3);
      uint4 ha = *(const uint4*)&Hin[(size_t)s0*128 + ql*8];
      uint4 hb = *(const uint4*)&Hin[(size_t)s1*128 + ql*8];
      uint4 hc = *(const uint4*)&Hin[(size_t)s2*128 + ql*8];
      uint4 hd = *(const uint4*)&Hin[(size_t)s3*128 + ql*8];
      denom += (w0 + w1) + (w2 + w3);
      acc[0]+=w0*bf16lo(ha.x)+w1*bf16lo(hb.x)+w2*bf16lo(hc.x)+w3*bf16lo(hd.x);
      acc[1]+=w0*bf16hi(ha.x)+w1*bf16hi(hb.x)+w2*bf16hi(hc.x)+w3*bf16hi(hd.x);
      acc[2]+=w0*bf16lo(ha.y)+w1*bf16lo(hb.y)+w2*bf16lo(hc.y)+w3*bf16lo(hd.y);
      acc[3]+=w0*bf16hi(ha.y)+w1*bf16hi(hb.y)+w2*bf16hi(hc.y)+w3*bf16hi(hd.y);
      acc[4]+=w0*bf16lo(ha.z)+w1*bf16lo(hb.z)+w2*bf16lo(hc.z)+w3*bf16lo(hd.z);
      acc[5]+=w0*bf16hi(ha.z)+w1*bf16hi(hb.z)+w2*bf16hi(hc.z)+w3*bf16hi(hd.z);
      acc[6]+=w0*bf16lo(ha.w)+w1*bf16lo(hb.w)+w2*bf16lo(hc.w)+w3*bf16lo(hd.w);
      acc[7]+=w0*bf16hi(ha.w)+w1*bf16hi(hb.w)+w2*bf16hi(hc.w)+w3*bf16hi(hd.w);
    }
  }
  denom += __shfl_xor(denom,16); denom += __shfl_xor(denom,32);
  #pragma unroll
  for (int k=0;k<8;k++){ acc[k]+=__shfl_xor(acc[k],16); acc[k]+=__shfl_xor(acc[k],32); }
  if (qw == 0){
    float inv = 1.0f / denom;          // >=1 term (self loop)
    float ps = 0.f, pd = 0.f;
    unsigned short o[8];
    #pragma unroll
    for (int k=0;k<8;k++){
      float v = fmaxf(acc[k]*inv + bias[ql*8+k], 0.f);   // relu (layer1 only)
      o[k] = bf16bits(v);
      ps += v * vas[ql*8+k];
      pd += v * vad[ql*8+k];
    }
    *(uint4*)&outp[(size_t)wid*128 + ql*8] = *(uint4*)o;
    #pragma unroll
    for (int d=1; d<16; d<<=1){ ps += __shfl_xor(ps,d); pd += __shfl_xor(pd,d); }
    if (ql == 0){ as2[wid] = ps; ad2[wid] = pd; }
  }
}

// --- gemm2: h2 = hrelu @ W2 (no alpha fusion) ---
__global__ __launch_bounds__(256) void gemm2_k(
    const unsigned short* __restrict__ A, const unsigned short* __restrict__ Wt,
    unsigned short* __restrict__ H, int M)
{
  __shared__ unsigned short smem[64*136 + 64*136];
  gemm_body<64, false>(nullptr, A, Wt, nullptr, nullptr, H, nullptr, nullptr,
                       M, blockIdx.x*64, smem, smem + 64*136);
}

// --- F=64 aggregation: eighth-waves, 32 edges/iter (4 gathers in flight) ---
__global__ __launch_bounds__(256) void edge_agg64(
    const int* __restrict__ offs, const int* __restrict__ srcS,
    const float* __restrict__ asrc, const float* __restrict__ adst,
    const unsigned short* __restrict__ Hin, const float* __restrict__ bias,
    float* __restrict__ outp, int n)
{
  int wid  = (blockIdx.x * 256 + threadIdx.x) >> 6;
  int lane = threadIdx.x & 63;
  if (wid >= n) return;
  int beg = offs[wid], end = offs[wid+1];
  float ad = adst[wid];
  int ew = lane >> 3, el = lane & 7;
  float acc[8] = {}; float denom = 0.f;
  for (int base = beg; base < end; base += 64){
    int m = end - base; if (m > 64) m = 64;
    int   sv = (lane < m) ? srcS[base + lane] : 0;
    float av = (lane < m) ? asrc[sv] : 0.f;
    float ev = av + ad;
    ev = (ev > 0.f) ? ev : 0.2f*ev;
    float wv = (lane < m) ? __expf(ev) : 0.f;
    for (int j = 0; j < m; j += 32){
      int i0 = j+ew, i1 = j+8+ew, i2 = j+16+ew, i3 = j+24+ew;   // <=63
      int   s0 = __shfl(sv,i0), s1 = __shfl(sv,i1), s2 = __shfl(sv,i2), s3 = __shfl(sv,i3);
      float w0 = __shfl(wv,i0), w1 = __shfl(wv,i1), w2 = __shfl(wv,i2), w3 = __shfl(wv,i3);
      uint4 ha = *(const uint4*)&Hin[(size_t)s0*64 + el*8];
      uint4 hb = *(const uint4*)&Hin[(size_t)s1*64 + el*8];
      uint4 hc = *(const uint4*)&Hin[(size_t)s2*64 + el*8];
      uint4 hd = *(const uint4*)&Hin[(size_t)s3*64 + el*8];
      denom += (w0 + w1) + (w2 + w3);
      acc[0]+=w0*bf16lo(ha.x)+w1*bf16lo(hb.x)+w2*bf16lo(hc.x)+w3*bf16lo(hd.x);
      acc[1]+=w0*bf16hi(ha.x)+w1*bf16hi(hb.x)+w2*bf16hi(hc.x)+w3*bf16hi(hd.x);
      acc[2]+=w0*bf16lo(ha.y)+w1*bf16lo(hb.y)+w2*bf16lo(hc.y)+w3*bf16lo(hd.y);
      acc[3]+=w0*bf16hi(ha.y)+w1*bf16hi(hb.y)+w2*bf16hi(hc.y)+w3*bf16hi(hd.y);
      acc[4]+=w0*bf16lo(ha.z)+w1*bf16lo(hb.z)+w2*bf16lo(hc.z)+w3*bf16lo(hd.z);
      acc[5]+=w0*bf16hi(ha.z)+w1*bf16hi(hb.z)+w2*bf16hi(hc.z)+w3*bf16hi(hd.z);
      acc[6]+=w0*bf16lo(ha.w)+w1*bf16lo(hb.w)+w2*bf16lo(hc.w)+w3*bf16lo(hd.w);
      acc[7]+=w0*bf16hi(ha.w)+w1*bf16hi(hb.w)+w2*bf16hi(hc.w)+w3*bf16hi(hd.w);
    }
  }
  denom += __shfl_xor(denom,8); denom += __shfl_xor(denom,16); denom += __shfl_xor(denom,32);
  #pragma unroll
  for (int k=0;k<8;k++){
    acc[k]+=__shfl_xor(acc[k],8); acc[k]+=__shfl_xor(acc[k],16); acc[k]+=__shfl_xor(acc[k],32);
  }
  if (ew == 0){
    float inv = 1.0f / denom;
    float4 o0, o1;
    o0.x = acc[0]*inv + bias[el*8+0]; o0.y = acc[1]*inv + bias[el*8+1];
    o0.z = acc[2]*inv + bias[el*8+2]; o0.w = acc[3]*inv + bias[el*8+3];
    o1.x = acc[4]*inv + bias[el*8+4]; o1.y = acc[5]*inv + bias[el*8+5];
    o1.z = acc[6]*inv + bias[el*8+6]; o1.w = acc[7]*inv + bias[el*8+7];
    *(float4*)&outp[(size_t)wid*64 + el*8]     = o0;
    *(float4*)&outp[(size_t)wid*64 + el*8 + 4] = o1;
  }
}

extern "C" void kernel_launch(void* const* d_in, const int* in_sizes, int n_in,
                              void* d_out, int out_size, void* d_ws, size_t ws_size,
                              hipStream_t stream) {
  const int IN = 128, HID = 128, OUT = 64;
  const int N = in_sizes[0] / IN;        // 50000
  const int E = in_sizes[1] / 2;         // 800000
  const int B = (N + 127) / 128;         // 391 buckets (<=512)
  const int SB = (E + 4095) / 4096;      // 196 scatter blocks

  const float* x    = (const float*)d_in[0];
  const int*   ei   = (const int*)d_in[1];
  const float* W1   = (const float*)d_in[2];
  const float* a1s  = (const float*)d_in[3];
  const float* a1d  = (const float*)d_in[4];
  const float* b1   = (const float*)d_in[5];
  const float* W2   = (const float*)d_in[6];
  const float* a2s  = (const float*)d_in[7];
  const float* a2d  = (const float*)d_in[8];
  const float* b2   = (const float*)d_in[9];
  float* out = (float*)d_out;

  char* w = (char*)d_ws;
  unsigned short* W1t = (unsigned short*)w; w += (size_t)HID*IN*2;
  unsigned short* W2t = (unsigned short*)w; w += (size_t)OUT*HID*2;
  unsigned short* h1    = (unsigned short*)w; w += (size_t)N*128*2;  // bf16
  unsigned short* hrelu = (unsigned short*)w; w += (size_t)N*128*2;  // bf16
  unsigned short* h2 = h1;               // alias: h1 dead before gemm2 writes h2
  float* as1   = (float*)w; w += (size_t)N*4;   // direct-stored by gemm1
  float* ad1   = (float*)w; w += (size_t)N*4;
  float* as2   = (float*)w; w += (size_t)N*4;   // direct-stored by edge_agg128
  float* ad2   = (float*)w; w += (size_t)N*4;
  float* vas   = (float*)w; w += 128*4;
  float* vad   = (float*)w; w += 128*4;
  int* offs    = (int*)w;   w += (size_t)(N+1)*4;
  int* bucketCount = (int*)w; w += 512*4;
  int* srcS    = (int*)w;   w += (size_t)(E+N)*4;
  unsigned int* gbuf = (unsigned int*)w; w += (size_t)B*BCAP*4;

  const int* esrc = ei;
  const int* edst = ei + E;

  hipLaunchKernelGGL(prep_all, dim3(50), dim3(256), 0, stream,
                     W1, W2, a2s, a2d, W1t, W2t, vas, vad, bucketCount);
  hipLaunchKernelGGL(scatter_or_gemm, dim3(SB + (N+63)/64), dim3(256), 0, stream,
                     esrc, edst, bucketCount, gbuf, E, SB,
                     x, W1t, a1s, a1d, h1, as1, ad1, N);
  hipLaunchKernelGGL(fine_sort, dim3(B), dim3(512), 0, stream,
                     gbuf, bucketCount, offs, srcS, N, E, B);
  hipLaunchKernelGGL(edge_agg128, dim3((N*64+255)/256), dim3(256), 0, stream,
                     offs, srcS, as1, ad1, h1, b1, hrelu, vas, vad, as2, ad2, N);
  hipLaunchKernelGGL(gemm2_k, dim3((N+63)/64), dim3(256), 0, stream,
                     hrelu, W2t, h2, N);
  hipLaunchKernelGGL(edge_agg64, dim3((N*64+255)/256), dim3(256), 0, stream,
                     offs, srcS, as2, ad2, h2, b2, out, N);
}